// Round 9
// baseline (1913.293 us; speedup 1.0000x reference)
//
#include <hip/hip_runtime.h>

#define BATCH 512
#define NN    32
#define NVT   32
#define HS    501
#define VS    533
#define KP    512

typedef short bf16x8 __attribute__((ext_vector_type(8)));
typedef float f32x4  __attribute__((ext_vector_type(4)));

__device__ __forceinline__ unsigned short f2bf(float f) {
    unsigned int u = __float_as_uint(f);
    u += 0x7fffu + ((u >> 16) & 1u);
    return (unsigned short)(u >> 16);
}
__device__ __forceinline__ float bf2f(unsigned short s) {
    return __uint_as_float(((unsigned int)s) << 16);
}
__device__ __forceinline__ float sigmoidf_(float x) { return 1.0f / (1.0f + __expf(-x)); }
__device__ __forceinline__ float tanhf_(float x)    { return 1.0f - 2.0f / (1.0f + __expf(2.0f * x)); }

// swizzled ushort index, [16][512] bf16 tile (row stride 1024 B); full formula per access
__device__ __forceinline__ int idx512(int row, int k) {
    return (((row << 10) + (k << 1)) ^ ((row & 7) << 4)) >> 1;
}
// swizzled ushort index, [16][256] bf16 tile (row stride 512 B)
__device__ __forceinline__ int idx256(int row, int k) {
    return (((row << 9) + (k << 1)) ^ ((row & 7) << 4)) >> 1;
}

#define N_WHH  (3 * KP * KP)
#define N_WGM  (2 * KP * KP)
#define N_GI   (3 * NVT * KP)
#define N_IDW  (2 * NN * KP)
#define N_WRT  (KP * NN)
#define N_ADJC (BATCH * NN)
#define N_TOT  (N_WHH + N_WGM + N_GI + N_IDW + N_WRT + N_ADJC)

__global__ void prep_kernel(const float* __restrict__ W_hh, const float* __restrict__ Wg,
                            const float* __restrict__ Wm, const float* __restrict__ W_ih,
                            const float* __restrict__ b_ih, const float* __restrict__ b_hh,
                            const float* __restrict__ bg, const float* __restrict__ W_reg,
                            const float* __restrict__ adj,
                            unsigned short* __restrict__ Whh_p, unsigned short* __restrict__ Wgm_p,
                            float* __restrict__ gi_tab, float* __restrict__ idw,
                            float* __restrict__ WregT, unsigned int* __restrict__ adjcG)
{
    for (int i = blockIdx.x * blockDim.x + threadIdx.x; i < N_TOT; i += gridDim.x * blockDim.x) {
        int j = i;
        if (j < N_WHH) {
            int g = j >> 18, rem = j & (KP * KP - 1);
            int h = rem >> 9, k = rem & (KP - 1);
            float val = 0.0f;
            if (h < HS) {
                if (k < HS)        val = W_hh[(size_t)(g * HS + h) * HS + k];
                else if (k == HS)  val = b_hh[g * HS + h];   // bias folded at k=501
            }
            Whh_p[j] = f2bf(val);
            continue;
        }
        j -= N_WHH;
        if (j < N_WGM) {
            int m = j >> 18, rem = j & (KP * KP - 1);
            int h = rem >> 9, k = rem & (KP - 1);
            const float* src = m ? Wm : Wg;
            Wgm_p[j] = (h < HS && k < HS) ? f2bf(src[(size_t)h * VS + k]) : (unsigned short)0;
            continue;
        }
        j -= N_WGM;
        if (j < N_GI) {
            int g = j >> 14, typ = (j >> 9) & 31, h = j & (KP - 1);
            gi_tab[j] = (h < HS) ? (W_ih[(size_t)(g * HS + h) * NVT + typ] + b_ih[g * HS + h]) : 0.0f;
            continue;
        }
        j -= N_GI;
        if (j < N_IDW) {
            int m = j >> 14, v = (j >> 9) & 31, h = j & (KP - 1);
            float val = 0.0f;
            if (h < HS)
                val = m ? Wm[(size_t)h * VS + HS + v]
                        : (Wg[(size_t)h * VS + HS + v] + bg[h]);
            idw[j] = val;
            continue;
        }
        j -= N_IDW;
        if (j < N_WRT) {
            int k = j >> 5, ii = j & 31;
            WregT[j] = (k < HS) ? W_reg[(size_t)ii * HS + k] : 0.0f;
            continue;
        }
        j -= N_WRT;
        {
            int b = j >> 5, vp = j & 31;
            unsigned int bits = 0;
            #pragma unroll
            for (int u = 0; u < 32; u++)
                bits |= (adj[((size_t)b * NN + u) * NN + vp] != 0.0f ? 1u : 0u) << u;
            adjcG[j] = bits;
        }
    }
}

// One kernel per DAG step v. Grid (32, 2), block 512 (8 waves).
// Block (bx, ky): owns 16 batch rows x 256-h slice (ky).
//  head : z = z_part[0]+z_part[1] -> G_{v-1} (persist, ky==0) -> gather Msg_v (LDS)
//  GEMM1: gh = Msg_v @ Whh^T (3 gates x 32 h per wave, K=512) + GRU -> Hv (LDS slice)
//  GEMM2: z_part[ky] = Hv_slice @ Wgm[:, kyslice]^T (K=256, all 1024 cols)
__global__ __launch_bounds__(512) void step_kernel(
    const unsigned short* __restrict__ Whh,   // [3*512][512] bf16 (k=501 = b_hh)
    const unsigned short* __restrict__ Wgm,   // [2*512][512] bf16
    const float* __restrict__ gi_tab,         // [3][32][512]
    const float* __restrict__ idw,            // [2][32][512]
    const int*   __restrict__ types,          // [512][32]
    const unsigned int* __restrict__ adjcG,   // [512][32] bitmask over u
    unsigned short* __restrict__ Gbuf,        // [32][512][512] bf16
    float* __restrict__ z_part,               // [2][512][1024] f32
    float* __restrict__ HvF,                  // [512][512] f32 (last step only)
    int v)
{
    __shared__ unsigned short Msgb[16 * 512];   // swizzled bf16 (GEMM1 A)
    __shared__ float          MsgFl[16 * 512];  // f32 (GRU blend)
    __shared__ unsigned short Hvb[16 * 256];    // swizzled bf16 (GEMM2 A)

    const int t = threadIdx.x;
    const int bb = blockIdx.x * 16;
    const int ky = blockIdx.y;
    const int lane = t & 63, w = t >> 6;
    const int c16 = lane & 15, kg = lane >> 4;

    // ---------------- head: rebuild G_{v-1}, gather Msg_v ----------------
    {
        const int b = t >> 5;              // 0..15
        const int h0 = (t & 31) * 16;      // 0..496
        float msg[16];
        if (v == 0) {
            #pragma unroll
            for (int x = 0; x < 16; x++) msg[x] = 0.0f;
        } else {
            const float* zp0 = z_part + (((size_t)(bb + b)) << 10) + h0;
            const float* zp1 = zp0 + (1u << 19);
            const float* id0 = idw + (0 * NN + (v - 1)) * KP + h0;
            const float* id1 = idw + (1 * NN + (v - 1)) * KP + h0;
            unsigned short gbits[16];
            #pragma unroll
            for (int x = 0; x < 16; x++) {
                const int h = h0 + x;
                float g = 0.0f;
                if (h < HS) {
                    const float zg = zp0[x] + zp1[x] + id0[x];
                    const float zm = zp0[512 + x] + zp1[512 + x] + id1[x];
                    g = sigmoidf_(zg) * zm;
                }
                gbits[x] = f2bf(g);
            }
            if (ky == 0) {   // persist G_{v-1} once
                unsigned short* gp = Gbuf + (((size_t)(v - 1) << 9) + (bb + b)) * KP + h0;
                *(bf16x8*)gp       = *(const bf16x8*)&gbits[0];
                *(bf16x8*)(gp + 8) = *(const bf16x8*)&gbits[8];
            }
            unsigned int mask = adjcG[(bb + b) * NN + v];   // bits u < v (triu)
            const float gsel = ((mask >> (v - 1)) & 1u) ? 1.0f : 0.0f;
            #pragma unroll
            for (int x = 0; x < 16; x++) msg[x] = gsel * bf2f(gbits[x]);
            mask &= (v >= 1) ? ((1u << (v - 1)) - 1u) : 0u;
            while (mask) {
                const int u = __builtin_ctz(mask); mask &= mask - 1u;
                const unsigned short* gp = Gbuf + (((size_t)u << 9) + (bb + b)) * KP + h0;
                const bf16x8 ga = *(const bf16x8*)gp;
                const bf16x8 gc = *(const bf16x8*)(gp + 8);
                #pragma unroll
                for (int x = 0; x < 8; x++) {
                    msg[x]     += bf2f((unsigned short)ga[x]);
                    msg[8 + x] += bf2f((unsigned short)gc[x]);
                }
            }
        }
        if (h0 <= HS && HS < h0 + 16) msg[HS - h0] = 1.0f;   // bias column k=501
        #pragma unroll
        for (int x = 0; x < 16; x++) {
            MsgFl[b * KP + h0 + x] = msg[x];
            Msgb[idx512(b, h0 + x)] = f2bf(msg[x]);
        }
    }
    __syncthreads();

    // ---------------- GEMM1: gh = Msg @ Whh^T ----------------
    f32x4 acc[3][2];
    #pragma unroll
    for (int g = 0; g < 3; g++)
        #pragma unroll
        for (int q = 0; q < 2; q++) acc[g][q] = (f32x4){0.f,0.f,0.f,0.f};
    {
        const int hbase = ky * 256 + w * 32;
        const unsigned short* wB[3][2];
        #pragma unroll
        for (int g = 0; g < 3; g++)
            #pragma unroll
            for (int q = 0; q < 2; q++)
                wB[g][q] = Whh + (((size_t)(g * KP + hbase + q * 16 + c16)) << 9) + kg * 8;
        #pragma unroll
        for (int kk = 0; kk < 16; kk++) {
            const bf16x8 af = *(const bf16x8*)&Msgb[idx512(c16, kg * 8 + kk * 32)];
            #pragma unroll
            for (int g = 0; g < 3; g++)
                #pragma unroll
                for (int q = 0; q < 2; q++)
                    acc[g][q] = __builtin_amdgcn_mfma_f32_16x16x32_bf16(
                        af, *(const bf16x8*)(wB[g][q] + kk * 32), acc[g][q], 0, 0, 0);
        }
    }
    // ---------------- GRU epilogue -> Hvb (LDS), HvF at v=31 ----------------
    const bool last = (v == NN - 1);
    #pragma unroll
    for (int q = 0; q < 2; q++) {
        const int hl = w * 32 + q * 16 + c16;     // 0..255 local
        const int h  = ky * 256 + hl;
        const bool ok = (h < HS);
        #pragma unroll
        for (int j = 0; j < 4; j++) {
            const int bl = kg * 4 + j;
            const int b  = bb + bl;
            float hv = 0.0f;
            if (ok) {
                const int typ = types[b * NN + v];
                const float gr = gi_tab[(0 * NVT + typ) * KP + h];
                const float gz = gi_tab[(1 * NVT + typ) * KP + h];
                const float gn = gi_tab[(2 * NVT + typ) * KP + h];
                const float hmsg = MsgFl[bl * KP + h];
                const float r = sigmoidf_(gr + acc[0][q][j]);
                const float z = sigmoidf_(gz + acc[1][q][j]);
                const float n = tanhf_(gn + r * acc[2][q][j]);
                hv = (1.0f - z) * n + z * hmsg;
            }
            Hvb[idx256(bl, hl)] = f2bf(hv);
            if (last) HvF[((size_t)b << 9) + h] = hv;
        }
    }
    if (last) return;
    __syncthreads();

    // ---------------- GEMM2: z_part[ky] = Hv_slice @ Wgm[:,kyslice]^T ----------------
    f32x4 zacc[8];
    #pragma unroll
    for (int i = 0; i < 8; i++) zacc[i] = (f32x4){0.f,0.f,0.f,0.f};
    {
        const unsigned short* wB[8];
        #pragma unroll
        for (int i = 0; i < 8; i++)
            wB[i] = Wgm + (((size_t)(w * 128 + i * 16 + c16)) << 9) + ky * 256 + kg * 8;
        #pragma unroll
        for (int kk = 0; kk < 8; kk++) {
            const bf16x8 af = *(const bf16x8*)&Hvb[idx256(c16, kg * 8 + kk * 32)];
            #pragma unroll
            for (int i = 0; i < 8; i++)
                zacc[i] = __builtin_amdgcn_mfma_f32_16x16x32_bf16(
                    af, *(const bf16x8*)(wB[i] + kk * 32), zacc[i], 0, 0, 0);
        }
    }
    {
        float* zp = z_part + ((size_t)ky << 19);
        #pragma unroll
        for (int i = 0; i < 8; i++)
            #pragma unroll
            for (int j = 0; j < 4; j++)
                zp[(((size_t)(bb + kg * 4 + j)) << 10) + w * 128 + i * 16 + c16] = zacc[i][j];
    }
}

// mu = Hv31 @ W_reg^T + b_reg
__global__ __launch_bounds__(256) void final_kernel(
    const float* __restrict__ HvF,       // [512][512]
    const float* __restrict__ WregT,     // [512][32]
    const float* __restrict__ b_reg,     // [32]
    float* __restrict__ out)             // [512][32]
{
    const int t = blockIdx.x * 256 + threadIdx.x;
    const int b = t >> 5, i = t & 31;
    float s = b_reg[i];
    const float* hp = HvF + ((size_t)b << 9);
    #pragma unroll 4
    for (int k = 0; k < KP; k++) s += hp[k] * WregT[k * 32 + i];
    out[b * 32 + i] = s;
}

extern "C" void kernel_launch(void* const* d_in, const int* in_sizes, int n_in,
                              void* d_out, int out_size, void* d_ws, size_t ws_size,
                              hipStream_t stream) {
    const int*   node_types = (const int*)  d_in[0];
    const float* adj        = (const float*)d_in[1];
    const float* Wg         = (const float*)d_in[2];
    const float* bg         = (const float*)d_in[3];
    const float* Wm         = (const float*)d_in[4];
    const float* W_ih       = (const float*)d_in[5];
    const float* b_ih       = (const float*)d_in[6];
    const float* W_hh       = (const float*)d_in[7];
    const float* b_hh       = (const float*)d_in[8];
    const float* W_reg      = (const float*)d_in[9];
    const float* b_reg      = (const float*)d_in[10];
    float* out = (float*)d_out;

    char* p = (char*)d_ws;
    unsigned short* Whh_p = (unsigned short*)p; p += (size_t)N_WHH * 2;
    unsigned short* Wgm_p = (unsigned short*)p; p += (size_t)N_WGM * 2;
    float* gi_tab = (float*)p; p += (size_t)N_GI * 4;
    float* idw    = (float*)p; p += (size_t)N_IDW * 4;
    float* WregT  = (float*)p; p += (size_t)N_WRT * 4;
    float* HvF    = (float*)p; p += (size_t)BATCH * KP * 4;
    float* z_part = (float*)p; p += (size_t)2 * BATCH * 1024 * 4;
    unsigned int* adjcG = (unsigned int*)p; p += (size_t)N_ADJC * 4;
    unsigned short* Gbuf = (unsigned short*)p; p += (size_t)NN * BATCH * KP * 2;

    prep_kernel<<<4096, 256, 0, stream>>>(W_hh, Wg, Wm, W_ih, b_ih, b_hh, bg, W_reg, adj,
                                          Whh_p, Wgm_p, gi_tab, idw, WregT, adjcG);

    dim3 grd(BATCH / 16, 2);   // 32 x 2 = 64 blocks
    for (int v = 0; v < NN; v++)
        step_kernel<<<grd, 512, 0, stream>>>(Whh_p, Wgm_p, gi_tab, idw, node_types,
                                             adjcG, Gbuf, z_part, HvF, v);
    final_kernel<<<(BATCH * NN) / 256, 256, 0, stream>>>(HvF, WregT, b_reg, out);
}

// Round 10
// 752.619 us; speedup vs baseline: 2.5422x; 2.5422x over previous
//
#include <hip/hip_runtime.h>

#define BATCH 512
#define NN    32
#define NVT   32
#define HS    501
#define VS    533
#define KP    512

typedef short bf16x8 __attribute__((ext_vector_type(8)));
typedef float f32x4  __attribute__((ext_vector_type(4)));

__device__ __forceinline__ unsigned short f2bf(float f) {
    unsigned int u = __float_as_uint(f);
    u += 0x7fffu + ((u >> 16) & 1u);
    return (unsigned short)(u >> 16);
}
__device__ __forceinline__ float bf2f(unsigned short s) {
    return __uint_as_float(((unsigned int)s) << 16);
}
__device__ __forceinline__ float sigmoidf_(float x) { return 1.0f / (1.0f + __expf(-x)); }
__device__ __forceinline__ float tanhf_(float x)    { return 1.0f - 2.0f / (1.0f + __expf(2.0f * x)); }

#define N_WHH  (3 * KP * KP)
#define N_WGM  (2 * KP * KP)
#define N_GI   (3 * NVT * KP)
#define N_IDW  (2 * NN * KP)
#define N_WRT  (KP * NN)
#define N_MSGB (BATCH * KP)
#define N_MSGF (BATCH * KP)
#define N_ADJC (BATCH * NN)
#define N_TOT  (N_WHH + N_WGM + N_GI + N_IDW + N_WRT + N_MSGB + N_MSGF + N_ADJC)

// One-time: bf16 weight repack (b_hh folded at k=501), gi table, id/bg table,
// WregT, Msg init (bf16 + f32), adjacency column bitmasks.
__global__ void prep_kernel(const float* __restrict__ W_hh, const float* __restrict__ Wg,
                            const float* __restrict__ Wm, const float* __restrict__ W_ih,
                            const float* __restrict__ b_ih, const float* __restrict__ b_hh,
                            const float* __restrict__ bg, const float* __restrict__ W_reg,
                            const float* __restrict__ adj,
                            unsigned short* __restrict__ Whh_p, unsigned short* __restrict__ Wgm_p,
                            float* __restrict__ gi_tab, float* __restrict__ idw,
                            float* __restrict__ WregT, unsigned short* __restrict__ MsgB,
                            float* __restrict__ MsgF, unsigned int* __restrict__ adjcG)
{
    for (int i = blockIdx.x * blockDim.x + threadIdx.x; i < N_TOT; i += gridDim.x * blockDim.x) {
        int j = i;
        if (j < N_WHH) {
            int g = j >> 18, rem = j & (KP * KP - 1);
            int h = rem >> 9, k = rem & (KP - 1);
            float val = 0.0f;
            if (h < HS) {
                if (k < HS)        val = W_hh[(size_t)(g * HS + h) * HS + k];
                else if (k == HS)  val = b_hh[g * HS + h];   // bias folded at k=501
            }
            Whh_p[j] = f2bf(val);
            continue;
        }
        j -= N_WHH;
        if (j < N_WGM) {
            int m = j >> 18, rem = j & (KP * KP - 1);
            int h = rem >> 9, k = rem & (KP - 1);
            const float* src = m ? Wm : Wg;
            Wgm_p[j] = (h < HS && k < HS) ? f2bf(src[(size_t)h * VS + k]) : (unsigned short)0;
            continue;
        }
        j -= N_WGM;
        if (j < N_GI) {
            int g = j >> 14, typ = (j >> 9) & 31, h = j & (KP - 1);
            gi_tab[j] = (h < HS) ? (W_ih[(size_t)(g * HS + h) * NVT + typ] + b_ih[g * HS + h]) : 0.0f;
            continue;
        }
        j -= N_GI;
        if (j < N_IDW) {
            int m = j >> 14, v = (j >> 9) & 31, h = j & (KP - 1);
            float val = 0.0f;
            if (h < HS)
                val = m ? Wm[(size_t)h * VS + HS + v]
                        : (Wg[(size_t)h * VS + HS + v] + bg[h]);
            idw[j] = val;
            continue;
        }
        j -= N_IDW;
        if (j < N_WRT) {
            int k = j >> 5, ii = j & 31;
            WregT[j] = (k < HS) ? W_reg[(size_t)ii * HS + k] : 0.0f;
            continue;
        }
        j -= N_WRT;
        if (j < N_MSGB) {
            int k = j & (KP - 1);
            MsgB[j] = (k == HS) ? (unsigned short)0x3F80 : (unsigned short)0;  // bias col = 1.0
            continue;
        }
        j -= N_MSGB;
        if (j < N_MSGF) { MsgF[j] = 0.0f; continue; }
        j -= N_MSGF;
        {
            int b = j >> 5, vp = j & 31;
            unsigned int bits = 0;
            #pragma unroll
            for (int u = 0; u < 32; u++)
                bits |= (adj[((size_t)b * NN + u) * NN + vp] != 0.0f ? 1u : 0u) << u;
            adjcG[j] = bits;
        }
    }
}

// Step A: gh = Msg @ Whh^T (3 gates) + GRU epilogue -> HvB (bf16) [+ HvF at v=31].
// grid (8 hy, 32 bx) -> bid%8 == hy: each XCD owns one 64-h weight slice, L2-hot
// across all steps. Block 256 (4 waves); wave = 16b x 16h, full K=512, no LDS.
__global__ __launch_bounds__(256) void gru_kernel(
    const unsigned short* __restrict__ MsgB,  // [512][512] bf16 (bias col 501 = 1)
    const float* __restrict__ MsgF,           // [512][512] f32
    const unsigned short* __restrict__ Whh,   // [3*512][512] bf16
    const float* __restrict__ gi_tab,         // [3][32][512]
    const int* __restrict__ types,            // [512][32]
    unsigned short* __restrict__ HvB,         // [512][512] bf16
    float* __restrict__ HvF,                  // [512][512] f32 (last step)
    int v)
{
    const int t = threadIdx.x;
    const int lane = t & 63, w = t >> 6;
    const int c16 = lane & 15, kg = lane >> 4;
    const int bb = blockIdx.y * 16;
    const int hw = blockIdx.x * 64 + w * 16;

    const unsigned short* Ar = MsgB + (((size_t)(bb + c16)) << 9) + kg * 8;
    const unsigned short* w0 = Whh + (((size_t)(0 * KP + hw + c16)) << 9) + kg * 8;
    const unsigned short* w1 = Whh + (((size_t)(1 * KP + hw + c16)) << 9) + kg * 8;
    const unsigned short* w2 = Whh + (((size_t)(2 * KP + hw + c16)) << 9) + kg * 8;

    f32x4 a0 = {0.f,0.f,0.f,0.f}, a1 = a0, a2 = a0;
    #pragma unroll
    for (int kk = 0; kk < 16; kk++) {
        const bf16x8 af = *(const bf16x8*)(Ar + kk * 32);
        a0 = __builtin_amdgcn_mfma_f32_16x16x32_bf16(af, *(const bf16x8*)(w0 + kk * 32), a0, 0, 0, 0);
        a1 = __builtin_amdgcn_mfma_f32_16x16x32_bf16(af, *(const bf16x8*)(w1 + kk * 32), a1, 0, 0, 0);
        a2 = __builtin_amdgcn_mfma_f32_16x16x32_bf16(af, *(const bf16x8*)(w2 + kk * 32), a2, 0, 0, 0);
    }

    const int h = hw + c16;
    const bool ok = (h < HS);
    const bool last = (v == NN - 1);
    #pragma unroll
    for (int j = 0; j < 4; j++) {
        const int b = bb + kg * 4 + j;
        float hv = 0.0f;
        if (ok) {
            const int typ = types[b * NN + v];
            const float gr = gi_tab[(0 * NVT + typ) * KP + h];
            const float gz = gi_tab[(1 * NVT + typ) * KP + h];
            const float gn = gi_tab[(2 * NVT + typ) * KP + h];
            const float hmsg = MsgF[((size_t)b << 9) + h];
            const float r = sigmoidf_(gr + a0[j]);
            const float z = sigmoidf_(gz + a1[j]);
            const float n = tanhf_(gn + r * a2[j]);
            hv = (1.0f - z) * n + z * hmsg;
        }
        HvB[((size_t)b << 9) + h] = f2bf(hv);
        if (last) HvF[((size_t)b << 9) + h] = hv;
    }
}

// Step B: z = Hv @ {Wg,Wm}^T ; G_v = sigmoid(zg+id+bg)*(zm+id) -> Gbuf;
// gather Msg_{v+1}[b,h] = sum_{u<=v} edge(u,v+1) * G_u[b,h]  (+bias col).
// grid (8 hy, 32 bx), block 256; wave = 16b x 16h, full K, no LDS.
__global__ __launch_bounds__(256) void gate_kernel(
    const unsigned short* __restrict__ HvB,   // [512][512] bf16
    const unsigned short* __restrict__ Wgm,   // [2*512][512] bf16
    const float* __restrict__ idw,            // [2][32][512]
    const unsigned int* __restrict__ adjcG,   // [512][32] bitmask over u
    unsigned short* __restrict__ Gbuf,        // [32][512][512] bf16
    unsigned short* __restrict__ MsgB,        // [512][512] bf16
    float* __restrict__ MsgF,                 // [512][512] f32
    int v)
{
    const int t = threadIdx.x;
    const int lane = t & 63, w = t >> 6;
    const int c16 = lane & 15, kg = lane >> 4;
    const int bb = blockIdx.y * 16;
    const int hw = blockIdx.x * 64 + w * 16;

    const unsigned short* Ar = HvB + (((size_t)(bb + c16)) << 9) + kg * 8;
    const unsigned short* w0 = Wgm + (((size_t)(0 * KP + hw + c16)) << 9) + kg * 8;
    const unsigned short* w1 = Wgm + (((size_t)(1 * KP + hw + c16)) << 9) + kg * 8;

    f32x4 b0 = {0.f,0.f,0.f,0.f}, b1 = b0;
    #pragma unroll
    for (int kk = 0; kk < 16; kk++) {
        const bf16x8 af = *(const bf16x8*)(Ar + kk * 32);
        b0 = __builtin_amdgcn_mfma_f32_16x16x32_bf16(af, *(const bf16x8*)(w0 + kk * 32), b0, 0, 0, 0);
        b1 = __builtin_amdgcn_mfma_f32_16x16x32_bf16(af, *(const bf16x8*)(w1 + kk * 32), b1, 0, 0, 0);
    }

    const int h = hw + c16;
    const bool ok = (h < HS);
    const float id0 = ok ? idw[(0 * NN + v) * KP + h] : 0.0f;
    const float id1 = ok ? idw[(1 * NN + v) * KP + h] : 0.0f;

    #pragma unroll
    for (int j = 0; j < 4; j++) {
        const int b = bb + kg * 4 + j;
        float gq = 0.0f;
        if (ok) gq = sigmoidf_(b0[j] + id0) * (b1[j] + id1);
        const unsigned short gbits = f2bf(gq);
        Gbuf[(((size_t)v << 9) + b) * KP + h] = gbits;

        float msg = 0.0f;
        unsigned int mask = adjcG[b * NN + (v + 1)];     // bits u <= v only (triu)
        if ((mask >> v) & 1u) { msg += bf2f(gbits); mask &= ~(1u << v); }
        while (mask) {
            const int u = __builtin_ctz(mask); mask &= mask - 1u;
            msg += bf2f(Gbuf[(((size_t)u << 9) + b) * KP + h]);
        }
        if (h == HS) msg = 1.0f;                          // bias column
        MsgB[((size_t)b << 9) + h] = f2bf(msg);
        MsgF[((size_t)b << 9) + h] = msg;
    }
}

// mu = Hv31 @ W_reg^T + b_reg
__global__ __launch_bounds__(256) void final_kernel(
    const float* __restrict__ HvF,       // [512][512]
    const float* __restrict__ WregT,     // [512][32]
    const float* __restrict__ b_reg,     // [32]
    float* __restrict__ out)             // [512][32]
{
    const int t = blockIdx.x * 256 + threadIdx.x;
    const int b = t >> 5, i = t & 31;
    float s = b_reg[i];
    const float* hp = HvF + ((size_t)b << 9);
    #pragma unroll 4
    for (int k = 0; k < KP; k++) s += hp[k] * WregT[k * 32 + i];
    out[b * 32 + i] = s;
}

extern "C" void kernel_launch(void* const* d_in, const int* in_sizes, int n_in,
                              void* d_out, int out_size, void* d_ws, size_t ws_size,
                              hipStream_t stream) {
    const int*   node_types = (const int*)  d_in[0];
    const float* adj        = (const float*)d_in[1];
    const float* Wg         = (const float*)d_in[2];
    const float* bg         = (const float*)d_in[3];
    const float* Wm         = (const float*)d_in[4];
    const float* W_ih       = (const float*)d_in[5];
    const float* b_ih       = (const float*)d_in[6];
    const float* W_hh       = (const float*)d_in[7];
    const float* b_hh       = (const float*)d_in[8];
    const float* W_reg      = (const float*)d_in[9];
    const float* b_reg      = (const float*)d_in[10];
    float* out = (float*)d_out;

    char* p = (char*)d_ws;
    unsigned short* Whh_p = (unsigned short*)p; p += (size_t)N_WHH * 2;
    unsigned short* Wgm_p = (unsigned short*)p; p += (size_t)N_WGM * 2;
    float* gi_tab = (float*)p; p += (size_t)N_GI * 4;
    float* idw    = (float*)p; p += (size_t)N_IDW * 4;
    float* WregT  = (float*)p; p += (size_t)N_WRT * 4;
    unsigned short* MsgB = (unsigned short*)p; p += (size_t)N_MSGB * 2;
    float* MsgF   = (float*)p; p += (size_t)N_MSGF * 4;
    unsigned short* HvB  = (unsigned short*)p; p += (size_t)BATCH * KP * 2;
    float* HvF    = (float*)p; p += (size_t)BATCH * KP * 4;
    unsigned int* adjcG  = (unsigned int*)p;  p += (size_t)N_ADJC * 4;
    unsigned short* Gbuf = (unsigned short*)p; p += (size_t)NN * BATCH * KP * 2;

    prep_kernel<<<4096, 256, 0, stream>>>(W_hh, Wg, Wm, W_ih, b_ih, b_hh, bg, W_reg, adj,
                                          Whh_p, Wgm_p, gi_tab, idw, WregT, MsgB, MsgF, adjcG);

    dim3 grd(KP / 64, BATCH / 16);   // (8 hy, 32 bx): bid%8 == hy -> XCD-pinned weight slice
    for (int v = 0; v < NN; v++) {
        gru_kernel<<<grd, 256, 0, stream>>>(MsgB, MsgF, Whh_p, gi_tab, node_types, HvB, HvF, v);
        if (v < NN - 1)
            gate_kernel<<<grd, 256, 0, stream>>>(HvB, Wgm_p, idw, adjcG, Gbuf, MsgB, MsgF, v);
    }
    final_kernel<<<(BATCH * NN) / 256, 256, 0, stream>>>(HvF, WregT, b_reg, out);
}